// Round 4
// baseline (560.677 us; speedup 1.0000x reference)
//
#include <hip/hip_runtime.h>

// IndRNN: h_t = relu(x_t + w * h_{t-1}), w >= 0 (U(0,1)).
// R5: R4's decoupled-lookback scan with the synchronization fixed.
//
// R4 post-mortem (rocprof): FETCH 272 MB / WRITE 270 MB (= traffic floor,
// phase-C x re-read fully L3-absorbed) but only 2.17 TB/s, VALUBusy 5.7%.
// Cause: per-iteration ACQUIRE spin loads at agent scope each emit a
// whole-XCD-L2 buffer_inv (gfx950 L2s are non-coherent, so agent acquire
// = cache-wide invalidate); thousands per block while co-resident waves
// stream x through the same L2. Release stores likewise emitted per-block
// L2 writebacks inside the hot path.
// Fix: RELAXED spin loads (scope bits alone guarantee reading the
// coherence point; no inv), then ONE acquire fence per block; writer does
// ONE release fence + relaxed flag store from tid 0.
//
// Structure (unchanged): block (chunk c, group g) computes local composed
// F(h)=max(m,a+b*h) from its 256 KB x-slice, publishes (m,a), spins on
// <=31 predecessor flags, composes h_start in-register, replays exactly,
// writes out. All 1024 blocks co-resident (4 blocks/CU, VGPR=52).

#define T_STEPS 2048
#define B_DIM   32
#define H_DIM   1024
#define BH      (B_DIM * H_DIM)      // 32768 channels
#define BH4     (BH / 4)             // 8192 float4 quads per time row
#define NCHUNK  32                   // chunks along T
#define CLEN    (T_STEPS / NCHUNK)   // 64 steps per chunk
#define GRPS    (BH4 / 256)          // 32 channel-groups (blocks per chunk)
#define PF      8                    // prefetch depth (time steps)

typedef float f4 __attribute__((ext_vector_type(4)));

__device__ __forceinline__ f4 step_relu(const f4 w, const f4 h, const f4 x) {
    f4 r;
    r.x = fmaxf(fmaf(w.x, h.x, x.x), 0.f);
    r.y = fmaxf(fmaf(w.y, h.y, x.y), 0.f);
    r.z = fmaxf(fmaf(w.z, h.z, x.z), 0.f);
    r.w = fmaxf(fmaf(w.w, h.w, x.w), 0.f);
    return r;
}

__device__ __forceinline__ f4 step_lin(const f4 w, const f4 a, const f4 x) {
    f4 r;
    r.x = fmaf(w.x, a.x, x.x);
    r.y = fmaf(w.y, a.y, x.y);
    r.z = fmaf(w.z, a.z, x.z);
    r.w = fmaf(w.w, a.w, x.w);
    return r;
}

__global__ void zero_flags(unsigned* __restrict__ f) {
    f[blockIdx.x * 256 + threadIdx.x] = 0u;
}

__global__ __launch_bounds__(256, 4)
void indrnn_lookback(const f4* __restrict__ x, const f4* __restrict__ h0,
                     const f4* __restrict__ w, f4* __restrict__ out,
                     f4* __restrict__ m_ws, f4* __restrict__ a_ws,
                     unsigned* __restrict__ flags)
{
    const int bid = blockIdx.x;
    const int c   = bid >> 5;            // chunk id (ascending dispatch)
    const int g   = bid & 31;            // channel group
    const int tid = threadIdx.x;
    const int q   = (g << 8) + tid;      // quad id 0..BH4-1

    const f4 wv = w[tid];                // per-H weight quad

    f4 b4 = wv;                          // b4 = w^64 via 6 squarings
#pragma unroll
    for (int i = 0; i < 6; ++i) {
        b4.x *= b4.x; b4.y *= b4.y; b4.z *= b4.z; b4.w *= b4.w;
    }

    const f4* xp = x + (size_t)c * CLEN * BH4 + q;

    f4 m, a, h0v;
    a.x = a.y = a.z = a.w = 0.f;
    if (c == 0) { h0v = h0[q]; m = h0v; }        // chunk 0: exact h0 seed
    else        { m.x = m.y = m.z = m.w = 0.f; } // identity start (h>=0 upstream)

    // ---------------- phase A: local composed function (m, a) ----------------
    f4 buf[PF];
#pragma unroll
    for (int i = 0; i < PF; ++i) buf[i] = xp[(size_t)i * BH4];

    int t0 = 0;
    for (; t0 + PF < CLEN; t0 += PF) {
        f4 nxt[PF];
#pragma unroll
        for (int i = 0; i < PF; ++i) nxt[i] = xp[(size_t)(t0 + PF + i) * BH4];
#pragma unroll
        for (int i = 0; i < PF; ++i) {
            m = step_relu(wv, m, buf[i]);
            a = step_lin(wv, a, buf[i]);
        }
#pragma unroll
        for (int i = 0; i < PF; ++i) buf[i] = nxt[i];
    }
#pragma unroll
    for (int i = 0; i < PF; ++i) {
        m = step_relu(wv, m, buf[i]);
        a = step_lin(wv, a, buf[i]);
    }

    // publish (m, a): stores drain to this XCD's L2 by the barrier's
    // vmcnt(0); ONE release fence (L2 writeback) + relaxed flag store.
    m_ws[(size_t)c * BH4 + q] = m;
    a_ws[(size_t)c * BH4 + q] = a;
    __syncthreads();
    if (tid == 0) {
        __builtin_amdgcn_fence(__ATOMIC_RELEASE, "agent");
        __hip_atomic_store(&flags[bid], 1u, __ATOMIC_RELAXED,
                           __HIP_MEMORY_SCOPE_AGENT);
    }

    // ---------------- lookback: h_start for this chunk ----------------
    f4 v;
    if (c == 0) {
        v = h0v;
    } else {
        if (tid < c) {                   // thread j spins on chunk j's flag
            const unsigned* fp = &flags[(tid << 5) | g];
            while (__hip_atomic_load(fp, __ATOMIC_RELAXED,
                                     __HIP_MEMORY_SCOPE_AGENT) == 0u)
                __builtin_amdgcn_s_sleep(1);
        }
        __syncthreads();                 // all predecessors published
        // ONE acquire fence per wave: invalidate stale L1/L2 lines
        // (previous graph iteration may have cached old m/a here).
        __builtin_amdgcn_fence(__ATOMIC_ACQUIRE, "agent");

        const f4* mp = m_ws + q;
        const f4* ap = a_ws + q;
        v = mp[0];                       // exact h after chunk 0 (h0-seeded)
#pragma unroll 4
        for (int j = 1; j < c; ++j) {
            const f4 mj = mp[(size_t)j * BH4];
            const f4 aj = ap[(size_t)j * BH4];
            v.x = fmaxf(fmaf(b4.x, v.x, aj.x), mj.x);
            v.y = fmaxf(fmaf(b4.y, v.y, aj.y), mj.y);
            v.z = fmaxf(fmaf(b4.z, v.z, aj.z), mj.z);
            v.w = fmaxf(fmaf(b4.w, v.w, aj.w), mj.w);
        }
    }

    // ---------------- phase C: replay exact recurrence, write out ----------------
    f4 h = v;
    f4* op = out + (size_t)c * CLEN * BH4 + q;

#pragma unroll
    for (int i = 0; i < PF; ++i) buf[i] = xp[(size_t)i * BH4];

    t0 = 0;
    for (; t0 + PF < CLEN; t0 += PF) {
        f4 nxt[PF];
#pragma unroll
        for (int i = 0; i < PF; ++i) nxt[i] = xp[(size_t)(t0 + PF + i) * BH4];
#pragma unroll
        for (int i = 0; i < PF; ++i) {
            h = step_relu(wv, h, buf[i]);
            op[(size_t)(t0 + i) * BH4] = h;
        }
#pragma unroll
        for (int i = 0; i < PF; ++i) buf[i] = nxt[i];
    }
#pragma unroll
    for (int i = 0; i < PF; ++i) {
        h = step_relu(wv, h, buf[i]);
        op[(size_t)(t0 + i) * BH4] = h;
    }
}

extern "C" void kernel_launch(void* const* d_in, const int* in_sizes, int n_in,
                              void* d_out, int out_size, void* d_ws, size_t ws_size,
                              hipStream_t stream) {
    const f4* x  = (const f4*)d_in[0];  // (T, B, H)
    const f4* h0 = (const f4*)d_in[1];  // (B, H)
    const f4* w  = (const f4*)d_in[2];  // (H,)
    f4* out = (f4*)d_out;               // (T, B, H)

    // workspace: m (4 MB) | a (4 MB) | flags (4 KB)
    float* m = (float*)d_ws;
    float* a = m + (size_t)NCHUNK * BH;
    unsigned* flags = (unsigned*)(a + (size_t)NCHUNK * BH);

    zero_flags<<<(NCHUNK * GRPS) / 256, 256, 0, stream>>>(flags);
    indrnn_lookback<<<NCHUNK * GRPS, 256, 0, stream>>>(
        x, h0, w, out, (f4*)m, (f4*)a, flags);
}

// Round 6
// 506.372 us; speedup vs baseline: 1.1072x; 1.1072x over previous
//
#include <hip/hip_runtime.h>

// IndRNN: h_t = relu(x_t + w * h_{t-1}), w >= 0 (U(0,1)).
// R7: two-kernel fence-free split (hang-proof).
//
// R6 (fused, fence-free via relaxed agent atomics) -> container died twice.
// Possible deadlock: its liveness depended on relaxed agent-scope stores
// writing through the non-coherent XCD L2 -- unverified. R7 removes ALL
// in-kernel cross-block synchronization: kernel launch boundaries provide
// ordering + cache maintenance (once per dispatch, vs 2048 per-block
// wb/inv fence ops in R4/R5, which ran at only 2.1 TB/s).
//
// k1: block (chunk c, group g) streams its 256 KB x-slice, computes the
//     chunk-composed function F(h)=max(m, a + w^64 h) coefficients (m,a).
//     Pure read stream -> its hbm_gbps measures the strided-read ceiling.
// k2: same block mapping; composes h_start from m/a of chunks < c
//     in-register (<=31 steps, L3-resident data), replays the exact
//     recurrence over its x-slice (L3-warm from k1), writes out.
//
// Traffic: k1 = 256 MB R + 8 MB W; k2 = ~8 MB R (L3) + 256 MB R (mostly
// L3) + 256 MB W. Algebra identical to R2-R6 (absmax 0.5, contractive).

#define T_STEPS 2048
#define B_DIM   32
#define H_DIM   1024
#define BH      (B_DIM * H_DIM)      // 32768 channels
#define BH4     (BH / 4)             // 8192 float4 quads per time row
#define NCHUNK  32                   // chunks along T
#define CLEN    (T_STEPS / NCHUNK)   // 64 steps per chunk
#define GRPS    (BH4 / 256)          // 32 channel-groups (blocks per chunk)
#define PF      8                    // prefetch depth (time steps)

typedef float f4 __attribute__((ext_vector_type(4)));

__device__ __forceinline__ f4 step_relu(const f4 w, const f4 h, const f4 x) {
    f4 r;
    r.x = fmaxf(fmaf(w.x, h.x, x.x), 0.f);
    r.y = fmaxf(fmaf(w.y, h.y, x.y), 0.f);
    r.z = fmaxf(fmaf(w.z, h.z, x.z), 0.f);
    r.w = fmaxf(fmaf(w.w, h.w, x.w), 0.f);
    return r;
}

__device__ __forceinline__ f4 step_lin(const f4 w, const f4 a, const f4 x) {
    f4 r;
    r.x = fmaf(w.x, a.x, x.x);
    r.y = fmaf(w.y, a.y, x.y);
    r.z = fmaf(w.z, a.z, x.z);
    r.w = fmaf(w.w, a.w, x.w);
    return r;
}

// ---------------- k1: per-chunk composed coefficients (m, a) ----------------
__global__ __launch_bounds__(256, 4)
void indrnn_coeff(const f4* __restrict__ x, const f4* __restrict__ h0,
                  const f4* __restrict__ w,
                  f4* __restrict__ m_ws, f4* __restrict__ a_ws)
{
    const int bid = blockIdx.x;
    const int c   = bid >> 5;            // chunk id
    const int g   = bid & 31;            // channel group
    const int tid = threadIdx.x;
    const int q   = (g << 8) + tid;      // quad id 0..BH4-1

    const f4 wv = w[tid];

    const f4* xp = x + (size_t)c * CLEN * BH4 + q;

    f4 m, a;
    a.x = a.y = a.z = a.w = 0.f;
    if (c == 0) { m = h0[q]; }                   // chunk 0: exact h0 seed
    else        { m.x = m.y = m.z = m.w = 0.f; } // identity start (h>=0 upstream)

    f4 buf[PF];
#pragma unroll
    for (int i = 0; i < PF; ++i) buf[i] = xp[(size_t)i * BH4];

    int t0 = 0;
    for (; t0 + PF < CLEN; t0 += PF) {
        f4 nxt[PF];
#pragma unroll
        for (int i = 0; i < PF; ++i) nxt[i] = xp[(size_t)(t0 + PF + i) * BH4];
#pragma unroll
        for (int i = 0; i < PF; ++i) {
            m = step_relu(wv, m, buf[i]);
            a = step_lin(wv, a, buf[i]);
        }
#pragma unroll
        for (int i = 0; i < PF; ++i) buf[i] = nxt[i];
    }
#pragma unroll
    for (int i = 0; i < PF; ++i) {
        m = step_relu(wv, m, buf[i]);
        a = step_lin(wv, a, buf[i]);
    }

    m_ws[(size_t)c * BH4 + q] = m;
    a_ws[(size_t)c * BH4 + q] = a;
}

// ---------------- k2: compose h_start, replay exactly, write out ----------------
__global__ __launch_bounds__(256, 4)
void indrnn_replay(const f4* __restrict__ x, const f4* __restrict__ h0,
                   const f4* __restrict__ w, f4* __restrict__ out,
                   const f4* __restrict__ m_ws, const f4* __restrict__ a_ws)
{
    const int bid = blockIdx.x;
    const int c   = bid >> 5;            // chunk id
    const int g   = bid & 31;            // channel group
    const int tid = threadIdx.x;
    const int q   = (g << 8) + tid;      // quad id 0..BH4-1

    const f4 wv = w[tid];

    f4 b4 = wv;                          // b4 = w^64 via 6 squarings
#pragma unroll
    for (int i = 0; i < 6; ++i) {
        b4.x *= b4.x; b4.y *= b4.y; b4.z *= b4.z; b4.w *= b4.w;
    }

    // ---- compose h_start for chunk c from (m, a) of chunks < c ----
    f4 v;
    if (c == 0) {
        v = h0[q];
    } else {
        const f4* mp = m_ws + q;
        const f4* ap = a_ws + q;
        v = mp[0];                       // exact h after chunk 0 (h0-seeded)
        for (int j = 1; j < c; ++j) {
            const f4 mj = mp[(size_t)j * BH4];
            const f4 aj = ap[(size_t)j * BH4];
            v.x = fmaxf(fmaf(b4.x, v.x, aj.x), mj.x);
            v.y = fmaxf(fmaf(b4.y, v.y, aj.y), mj.y);
            v.z = fmaxf(fmaf(b4.z, v.z, aj.z), mj.z);
            v.w = fmaxf(fmaf(b4.w, v.w, aj.w), mj.w);
        }
    }

    // ---- replay exact recurrence over this chunk's x-slice ----
    const f4* xp = x + (size_t)c * CLEN * BH4 + q;
    f4* op = out + (size_t)c * CLEN * BH4 + q;
    f4 h = v;

    f4 buf[PF];
#pragma unroll
    for (int i = 0; i < PF; ++i) buf[i] = xp[(size_t)i * BH4];

    int t0 = 0;
    for (; t0 + PF < CLEN; t0 += PF) {
        f4 nxt[PF];
#pragma unroll
        for (int i = 0; i < PF; ++i) nxt[i] = xp[(size_t)(t0 + PF + i) * BH4];
#pragma unroll
        for (int i = 0; i < PF; ++i) {
            h = step_relu(wv, h, buf[i]);
            op[(size_t)(t0 + i) * BH4] = h;
        }
#pragma unroll
        for (int i = 0; i < PF; ++i) buf[i] = nxt[i];
    }
#pragma unroll
    for (int i = 0; i < PF; ++i) {
        h = step_relu(wv, h, buf[i]);
        op[(size_t)(t0 + i) * BH4] = h;
    }
}

extern "C" void kernel_launch(void* const* d_in, const int* in_sizes, int n_in,
                              void* d_out, int out_size, void* d_ws, size_t ws_size,
                              hipStream_t stream) {
    const f4* x  = (const f4*)d_in[0];  // (T, B, H)
    const f4* h0 = (const f4*)d_in[1];  // (B, H)
    const f4* w  = (const f4*)d_in[2];  // (H,)
    f4* out = (f4*)d_out;               // (T, B, H)

    // workspace: m (4 MB) | a (4 MB)
    f4* m = (f4*)d_ws;
    f4* a = m + (size_t)NCHUNK * BH4;

    indrnn_coeff<<<NCHUNK * GRPS, 256, 0, stream>>>(x, h0, w, m, a);
    indrnn_replay<<<NCHUNK * GRPS, 256, 0, stream>>>(x, h0, w, out, m, a);
}